// Round 5
// baseline (13247.966 us; speedup 1.0000x reference)
//
#include <hip/hip_runtime.h>
#include <math.h>

#define TT 1024
#define DD 512

typedef unsigned int u32;
typedef unsigned long long u64;
typedef _Float16 half2_t __attribute__((ext_vector_type(2)));

// ---------------- tagged cross-block atomics (agent scope, relaxed; R2-proven) ----
static __device__ __forceinline__ u64 aload64(const u64* p) {
    return __hip_atomic_load(p, __ATOMIC_RELAXED, __HIP_MEMORY_SCOPE_AGENT);
}
static __device__ __forceinline__ void astore64(u64* p, u64 v) {
    __hip_atomic_store(p, v, __ATOMIC_RELAXED, __HIP_MEMORY_SCOPE_AGENT);
}
static __device__ __forceinline__ u32 pkh2(float lo, float hi) {
    return __builtin_bit_cast(u32, __builtin_amdgcn_cvt_pkrtz(lo, hi));
}
static __device__ __forceinline__ float2 uph2(u32 v) {
    half2_t h = __builtin_bit_cast(half2_t, v);
    return make_float2((float)h.x, (float)h.y);
}
static __device__ __forceinline__ u64 mkword(u32 pay, u32 tag) {
    return ((u64)tag << 32) | (u64)pay;
}

static __device__ __forceinline__ float redux16(float v) {
    v += __shfl_xor(v, 1); v += __shfl_xor(v, 2); v += __shfl_xor(v, 4); v += __shfl_xor(v, 8);
    return v;
}
static __device__ __forceinline__ float sum64(float v) {
    #pragma unroll
    for (int o = 32; o > 0; o >>= 1) v += __shfl_xor(v, o);
    return v;
}
static __device__ __forceinline__ float expc(float x) { return __expf(fminf(x, 60.f)); }
static __device__ __forceinline__ float fast_tanh(float x) {
    float xc = fminf(fmaxf(x, -15.f), 15.f);
    float e = __expf(2.f * xc);
    return (e - 1.f) / (e + 1.f);
}
// broadcast-buffer swizzle: element d at physical dword d ^ (((d>>5)&7)<<2)
static __device__ __forceinline__ int swz(int d) { return d ^ (((d >> 5) & 7) << 2); }

// ---------------- projection GEMM (unchanged) ----------------
__global__ __launch_bounds__(256) void proj_kernel(const float* __restrict__ x,
                                                   const float* __restrict__ Wxz,
                                                   float* __restrict__ xp,
                                                   float* __restrict__ z) {
    __shared__ float As[16][66];
    __shared__ float Bs[16][66];
    const int m0 = blockIdx.x * 64;
    const int n0 = blockIdx.y * 64;
    const int tid = threadIdx.x;
    const int tm = tid / 16, tn = tid % 16;
    float c[4][4] = {};
    for (int k0 = 0; k0 < 512; k0 += 16) {
        const int r = tid >> 2, c4 = (tid & 3) * 4;
        float4 a4 = *(const float4*)(x + (size_t)(m0 + r) * 512 + k0 + c4);
        float4 b4 = *(const float4*)(Wxz + (size_t)(n0 + r) * 512 + k0 + c4);
        As[c4 + 0][r] = a4.x; As[c4 + 1][r] = a4.y; As[c4 + 2][r] = a4.z; As[c4 + 3][r] = a4.w;
        Bs[c4 + 0][r] = b4.x; Bs[c4 + 1][r] = b4.y; Bs[c4 + 2][r] = b4.z; Bs[c4 + 3][r] = b4.w;
        __syncthreads();
        #pragma unroll
        for (int k = 0; k < 16; ++k) {
            float a0 = As[k][tm * 4 + 0], a1 = As[k][tm * 4 + 1];
            float a2 = As[k][tm * 4 + 2], a3 = As[k][tm * 4 + 3];
            float b0 = Bs[k][tn * 4 + 0], b1 = Bs[k][tn * 4 + 1];
            float b2 = Bs[k][tn * 4 + 2], b3 = Bs[k][tn * 4 + 3];
            c[0][0] += a0 * b0; c[0][1] += a0 * b1; c[0][2] += a0 * b2; c[0][3] += a0 * b3;
            c[1][0] += a1 * b0; c[1][1] += a1 * b1; c[1][2] += a1 * b2; c[1][3] += a1 * b3;
            c[2][0] += a2 * b0; c[2][1] += a2 * b1; c[2][2] += a2 * b2; c[2][3] += a2 * b3;
            c[3][0] += a3 * b0; c[3][1] += a3 * b1; c[3][2] += a3 * b2; c[3][3] += a3 * b3;
        }
        __syncthreads();
    }
    #pragma unroll
    for (int i = 0; i < 4; ++i) {
        const int m = m0 + tm * 4 + i;
        #pragma unroll
        for (int j = 0; j < 4; ++j) {
            const int e = n0 + tn * 4 + j;
            if (e < 512) xp[(size_t)m * 512 + e] = c[i][j];
            else         z[(size_t)m * 512 + (e - 512)] = c[i][j];
        }
    }
}

// ---------------- recurrence: 64 blocks = 8 batches x 8 d-chunks ----------------
// 1024-THREAD TAPE-IN-REGISTERS single-hop design. Thread (nrow=tid>>4, l=tid&15)
// owns tape[nrow][l*32..+31] in 8 float4 (full 64x512 replica per block). Per-
// thread resident: tape 32 + W_h 32 + W_write 32 = 96 VGPR -> fits the 128-VGPR
// bracket (16 waves/CU) WITHOUT spill (R3/R4 failure mode: demand 192 @ cap 128).
// LDS: only broadcast buffers (h, wv: 512 fl each, XOR-swizzled so strided b128
// reads are bank-conflict-free) + 64x68 rv scatter pad. Dataflow = R4 (verified).
__global__ __launch_bounds__(1024, 4) void rec_kernel(
    const float* __restrict__ tape0, const float* __restrict__ hwork0,
    const float* __restrict__ W_h, const float* __restrict__ b_h,
    const float* __restrict__ W_write,
    const float* __restrict__ g_z, const float* __restrict__ g_r,
    const float* __restrict__ g_h, const float* __restrict__ b_gate,
    const float* __restrict__ Zbuf,
    float* __restrict__ out, float* __restrict__ tape_out,
    u64* hA, u64* cA) {
    __shared__ __align__(16) float hw2f[512];      // full h(t), swizzled
    __shared__ __align__(16) float wvpf[2][512];   // wv double-buffer, swizzled
    __shared__ __align__(16) float red[64][68];    // rv scatter pad
    __shared__ float hnc[64], rvc[64];
    __shared__ float a_l[64], c1_l[64];
    __shared__ float ws_l[64], q0_l[64], hhc[64];
    __shared__ float hwv_s;

    const int b = blockIdx.x & 7, s = blockIdx.x >> 3;   // batch -> XCD, chunk
    const int tid = threadIdx.x, lane = tid & 63, wid = tid >> 6;
    const int nrow = tid >> 4, l = tid & 15, lswz = l & 7;
    const int half = tid & 1, jj = tid >> 1;             // W_write ownership
    const int d0 = s * 64;
    const float scale = 0.044194173824159216f;           // 1/sqrt(512)

    // --- resident state: 96 VGPRs ---
    float4 t4[8];     // tape[nrow][l*32 + 4i ..]
    float4 wh[8];     // W_h[d0+nrow][l*32 + 4i ..]
    float4 wwc[8];    // W_write[jj][d0 + half*32 + 4i ..]
    {
        const float4* ts = (const float4*)(tape0 + (size_t)(b * 64 + nrow) * DD + l * 32);
        #pragma unroll
        for (int j = 0; j < 8; ++j) t4[j] = ts[j];
        const float4* w1 = (const float4*)(W_h + (size_t)(d0 + nrow) * DD + l * 32);
        #pragma unroll
        for (int j = 0; j < 8; ++j) wh[j] = w1[j];
        const float4* w2 = (const float4*)(W_write + (size_t)jj * DD + d0 + half * 32);
        #pragma unroll
        for (int j = 0; j < 8; ++j) wwc[j] = w2[j];
    }
    float bhr = 0.f, gz = 0.f, gr = 0.f, gh = 0.f, bg = 0.f;
    if (wid == 0) bhr = b_h[d0 + lane];
    if (wid == 1) { gz = g_z[d0 + lane]; gr = g_r[d0 + lane]; gh = g_h[d0 + lane]; bg = b_gate[d0 + lane]; }

    // --- init LDS ---
    if (tid < 512) hw2f[swz(tid)] = hwork0[(size_t)b * DD + tid];
    ((float*)wvpf)[tid] = 0.f;                 // 1024 = 2*512 floats
    if (tid < 64) a_l[tid] = 0.f;
    float xpr = 0.f, zr = 0.f, hr = 0.f;
    if (wid == 0)      xpr = out[((size_t)(b * TT)) * DD + d0 + lane];
    else if (wid == 1) zr  = Zbuf[((size_t)(b * TT)) * DD + d0 + lane];
    __syncthreads();

    // --- bootstrap: q0 = h(-1).tape0, hh = W_h.h(-1) ---
    {
        float q0 = 0.f, hh = 0.f;
        #pragma unroll
        for (int i = 0; i < 8; ++i) {
            const int ph = l * 32 + 4 * (i ^ lswz);
            float4 h4 = *(const float4*)&hw2f[ph];
            q0 += t4[i].x * h4.x + t4[i].y * h4.y + t4[i].z * h4.z + t4[i].w * h4.w;
            hh += wh[i].x * h4.x + wh[i].y * h4.y + wh[i].z * h4.z + wh[i].w * h4.w;
        }
        q0 = redux16(q0); hh = redux16(hh);
        if (l == 0) { q0_l[nrow] = q0; hhc[nrow] = hh; }
    }
    __syncthreads();
    if (wid == 0) {
        float er = expc(scale * q0_l[lane]);
        float Zr = sum64(er);
        c1_l[lane] = __fdividef(er, Zr);       // a(-1)=0 -> c1 = r(0), c2 = 0
    }
    __syncthreads();
    if ((l >> 1) == s) {
        const float c1 = c1_l[nrow];
        #pragma unroll
        for (int i = 0; i < 8; ++i) {
            float4 v; v.x = c1 * t4[i].x; v.y = c1 * t4[i].y; v.z = c1 * t4[i].z; v.w = c1 * t4[i].w;
            *(float4*)&red[nrow][(l & 1) * 32 + 4 * i] = v;
        }
    }
    __syncthreads();
    if (wid == 0) {
        float rv = 0.f;
        #pragma unroll 8
        for (int r = 0; r < 64; ++r) rv += red[r][lane];
        float h = fast_tanh(xpr + hhc[lane] + rv + bhr);
        hr = h; hnc[lane] = h; rvc[lane] = rv;
    }
    __syncthreads();

    // ---------------- main scan ----------------
    for (int t = 0; t < TT; ++t) {
        const int p = t & 1;
        const u32 tg = (u32)(t + 1);
        float c2r = 0.f;

        // ---- P1: publish h(t) + c contributions; out(t); prefetch ----
        if (wid == 0) {
            float hn = __shfl_xor(hr, 1);
            if (!(lane & 1))
                astore64(&hA[((size_t)p * 8 + b) * 256 + s * 32 + (lane >> 1)],
                         mkword(pkh2(hr, hn), tg));
            if (t + 1 < TT) xpr = out[((size_t)(b * TT + t + 1)) * DD + d0 + lane];
        }
        {
            float cj = 0.f;
            #pragma unroll
            for (int i = 0; i < 8; ++i) {
                float4 h4 = *(const float4*)&hnc[half * 32 + 4 * i];
                cj += wwc[i].x * h4.x + wwc[i].y * h4.y + wwc[i].z * h4.z + wwc[i].w * h4.w;
            }
            cj += __shfl_xor(cj, 1);           // full cj for j = jj
            float cn = __shfl_xor(cj, 2);      // cj for j^1
            if (!(tid & 3))
                astore64(&cA[(((size_t)p * 8 + b) * 8 + s) * 256 + (tid >> 2)],
                         mkword(pkh2(cj, cn), tg));
        }
        if (wid == 1) {
            float h = hnc[lane];
            float g = zr * gz + rvc[lane] * gr + h * gh + bg;
            g = fminf(fmaxf(g, -20.f), 20.f);
            float sig = 1.f / (1.f + __expf(-g));
            out[((size_t)(b * TT + t)) * DD + d0 + lane] = h * g * sig;
            if (t + 1 < TT) zr = Zbuf[((size_t)(b * TT + t + 1)) * DD + d0 + lane];
        }

        // ---- P2: lerp (registers only), hop shadow ----
        {
            const float an = a_l[nrow];
            const float* wvO = wvpf[1 - p];
            #pragma unroll
            for (int i = 0; i < 8; ++i) {
                float4 w4 = *(const float4*)&wvO[l * 32 + 4 * (i ^ lswz)];
                t4[i].x += an * (w4.x - t4[i].x); t4[i].y += an * (w4.y - t4[i].y);
                t4[i].z += an * (w4.z - t4[i].z); t4[i].w += an * (w4.w - t4[i].w);
            }
        }

        // ---- P3: poll/gather: wv(t) (sum of 8 chunk contribs) + h(t) ----
        if (tid < 256) {
            const u64* cb = cA + (((size_t)p * 8 + b) * 8) * 256 + tid;
            u64 v0 = aload64(cb + 0 * 256), v1 = aload64(cb + 1 * 256);
            u64 v2 = aload64(cb + 2 * 256), v3 = aload64(cb + 3 * 256);
            u64 v4 = aload64(cb + 4 * 256), v5 = aload64(cb + 5 * 256);
            u64 v6 = aload64(cb + 6 * 256), v7 = aload64(cb + 7 * 256);
            for (;;) {
                u32 m = 0;
                if ((u32)(v0 >> 32) == tg) m |= 1u;   if ((u32)(v1 >> 32) == tg) m |= 2u;
                if ((u32)(v2 >> 32) == tg) m |= 4u;   if ((u32)(v3 >> 32) == tg) m |= 8u;
                if ((u32)(v4 >> 32) == tg) m |= 16u;  if ((u32)(v5 >> 32) == tg) m |= 32u;
                if ((u32)(v6 >> 32) == tg) m |= 64u;  if ((u32)(v7 >> 32) == tg) m |= 128u;
                if (m == 0xffu) break;
                __builtin_amdgcn_s_sleep(1);
                if (!(m & 1u))   v0 = aload64(cb + 0 * 256);
                if (!(m & 2u))   v1 = aload64(cb + 1 * 256);
                if (!(m & 4u))   v2 = aload64(cb + 2 * 256);
                if (!(m & 8u))   v3 = aload64(cb + 3 * 256);
                if (!(m & 16u))  v4 = aload64(cb + 4 * 256);
                if (!(m & 32u))  v5 = aload64(cb + 5 * 256);
                if (!(m & 64u))  v6 = aload64(cb + 6 * 256);
                if (!(m & 128u)) v7 = aload64(cb + 7 * 256);
            }
            float lo = 0.f, hi = 0.f; float2 f;
            f = uph2((u32)v0); lo += f.x; hi += f.y;
            f = uph2((u32)v1); lo += f.x; hi += f.y;
            f = uph2((u32)v2); lo += f.x; hi += f.y;
            f = uph2((u32)v3); lo += f.x; hi += f.y;
            f = uph2((u32)v4); lo += f.x; hi += f.y;
            f = uph2((u32)v5); lo += f.x; hi += f.y;
            f = uph2((u32)v6); lo += f.x; hi += f.y;
            f = uph2((u32)v7); lo += f.x; hi += f.y;
            const int d = 2 * tid;
            *(float2*)&wvpf[p][d ^ (((d >> 5) & 7) << 2)] = make_float2(lo, hi);
        } else if (tid < 512) {
            const int k = tid - 256;
            const u64* hb = hA + ((size_t)p * 8 + b) * 256 + k;
            u64 v = aload64(hb);
            for (;;) {
                if ((u32)(v >> 32) == tg) break;
                __builtin_amdgcn_s_sleep(1);
                v = aload64(hb);
            }
            float2 hp = uph2((u32)v);
            const int d = 2 * k;
            *(float2*)&hw2f[d ^ (((d >> 5) & 7) << 2)] = hp;
        }
        __syncthreads();                                   // B1

        // ---- P4: fused dots: ws = wv.tape^(t-1), q0 = h.tape^(t-1), hh = W_h.h ----
        {
            float ws = 0.f, q0 = 0.f, hh = 0.f;
            const float* wvP = wvpf[p];
            #pragma unroll
            for (int i = 0; i < 8; ++i) {
                const int ph = l * 32 + 4 * (i ^ lswz);
                float4 w4 = *(const float4*)&wvP[ph];
                float4 h4 = *(const float4*)&hw2f[ph];
                ws += w4.x * t4[i].x + w4.y * t4[i].y + w4.z * t4[i].z + w4.w * t4[i].w;
                q0 += h4.x * t4[i].x + h4.y * t4[i].y + h4.z * t4[i].z + h4.w * t4[i].w;
                hh += wh[i].x * h4.x + wh[i].y * h4.y + wh[i].z * h4.z + wh[i].w * h4.w;
            }
            ws = redux16(ws); q0 = redux16(q0); hh = redux16(hh);
            if (l == 0) { ws_l[nrow] = ws; q0_l[nrow] = q0; hhc[nrow] = hh; }
            if (nrow == 0) {                   // hwv = h(t).wv(t) on lanes 0..15
                float hwv = 0.f;
                #pragma unroll
                for (int i = 0; i < 8; ++i) {
                    const int ph = l * 32 + 4 * (i ^ lswz);
                    float4 w4 = *(const float4*)&wvP[ph];
                    float4 h4 = *(const float4*)&hw2f[ph];
                    hwv += w4.x * h4.x + w4.y * h4.y + w4.z * h4.z + w4.w * h4.w;
                }
                hwv = redux16(hwv);
                if (tid == 0) hwv_s = hwv;
            }
        }
        __syncthreads();                                   // B2

        // ---- P5: softmaxes (wave0); c2 stays in registers ----
        if (wid == 0) {
            float ew = expc(scale * ws_l[lane]);
            float Zw = sum64(ew);
            float a = __fdividef(ew, Zw);
            float q = (1.f - a) * q0_l[lane] + a * hwv_s;
            float er = expc(scale * q);
            float Zr = sum64(er);
            float r = __fdividef(er, Zr);
            a_l[lane] = a;
            c1_l[lane] = r * (1.f - a);
            c2r = sum64(r * a);
        }
        __syncthreads();                                   // B3

        // ---- P6: rv scatter (chunk-col owners) ----
        if ((l >> 1) == s) {
            const float c1 = c1_l[nrow];
            #pragma unroll
            for (int i = 0; i < 8; ++i) {
                float4 v; v.x = c1 * t4[i].x; v.y = c1 * t4[i].y; v.z = c1 * t4[i].z; v.w = c1 * t4[i].w;
                *(float4*)&red[nrow][(l & 1) * 32 + 4 * i] = v;
            }
        }
        __syncthreads();                                   // B4

        // ---- P7: wave0: rv(t+1) + h(t+1) ----
        if (wid == 0) {
            float rv = c2r * wvpf[p][swz(d0 + lane)];
            #pragma unroll 8
            for (int r = 0; r < 64; ++r) rv += red[r][lane];
            float h = fast_tanh(xpr + hhc[lane] + rv + bhr);
            hr = h; hnc[lane] = h; rvc[lane] = rv;
        }
        __syncthreads();                                   // B5
    }

    // ---- epilogue: final lerp (a(T-1), wv(T-1)=wvpf[1]) + write own chunk ----
    if ((l >> 1) == s) {
        const float an = a_l[nrow];
        float* dst = tape_out + ((size_t)(b * 64 + nrow)) * DD + d0 + (l & 1) * 32;
        #pragma unroll
        for (int i = 0; i < 8; ++i) {
            float4 w4 = *(const float4*)&wvpf[1][l * 32 + 4 * (i ^ lswz)];
            float4 v = t4[i];
            v.x += an * (w4.x - v.x); v.y += an * (w4.y - v.y);
            v.z += an * (w4.z - v.z); v.w += an * (w4.w - v.w);
            *(float4*)(dst + 4 * i) = v;
        }
    }
}

extern "C" void kernel_launch(void* const* d_in, const int* in_sizes, int n_in,
                              void* d_out, int out_size, void* d_ws, size_t ws_size,
                              hipStream_t stream) {
    const float* x       = (const float*)d_in[0];   // [8,1024,512]
    const float* tape0   = (const float*)d_in[1];   // [8,64,512]
    const float* hwork0  = (const float*)d_in[2];   // [8,512]
    const float* W_h     = (const float*)d_in[3];   // [512,512]
    const float* W_xz    = (const float*)d_in[4];   // [1024,512]
    const float* b_h     = (const float*)d_in[5];   // [512]
    const float* W_write = (const float*)d_in[6];   // [512,512]
    const float* g_z     = (const float*)d_in[7];
    const float* g_r     = (const float*)d_in[8];
    const float* g_h     = (const float*)d_in[9];
    const float* b_gate  = (const float*)d_in[10];

    float* out  = (float*)d_out;                        // outs [8,1024,512]
    float* tout = out + (size_t)8 * TT * DD;            // tape_final [8,64,512]

    char* ws = (char*)d_ws;
    u64* hA   = (u64*)ws;                               // [2][8][256]      = 32 KB
    u64* cA   = (u64*)(ws + 32768);                     // [2][8][8][256]   = 256 KB
    float* Zbuf = (float*)(ws + 393216);                // 16 MB

    (void)in_sizes; (void)n_in; (void)out_size; (void)ws_size;

    // tags equality-checked against monotone values; 0xAA poison never matches.
    dim3 pgrid(128, 16);
    proj_kernel<<<pgrid, 256, 0, stream>>>(x, W_xz, out, Zbuf);
    rec_kernel<<<64, 1024, 0, stream>>>(tape0, hwork0, W_h, b_h, W_write,
                                        g_z, g_r, g_h, b_gate, Zbuf,
                                        out, tout, hA, cA);
}

// Round 6
// 12021.587 us; speedup vs baseline: 1.1020x; 1.1020x over previous
//
#include <hip/hip_runtime.h>
#include <math.h>

#define TT 1024
#define DD 512

typedef unsigned int u32;
typedef unsigned long long u64;
typedef _Float16 half2_t __attribute__((ext_vector_type(2)));

// ---------------- tagged cross-block atomics (agent scope, relaxed; R2-proven) ----
static __device__ __forceinline__ u64 aload64(const u64* p) {
    return __hip_atomic_load(p, __ATOMIC_RELAXED, __HIP_MEMORY_SCOPE_AGENT);
}
static __device__ __forceinline__ void astore64(u64* p, u64 v) {
    __hip_atomic_store(p, v, __ATOMIC_RELAXED, __HIP_MEMORY_SCOPE_AGENT);
}
static __device__ __forceinline__ u32 pkh2(float lo, float hi) {
    return __builtin_bit_cast(u32, __builtin_amdgcn_cvt_pkrtz(lo, hi));
}
static __device__ __forceinline__ float2 uph2(u32 v) {
    half2_t h = __builtin_bit_cast(half2_t, v);
    return make_float2((float)h.x, (float)h.y);
}
static __device__ __forceinline__ u64 mkword(u32 pay, u32 tag) {
    return ((u64)tag << 32) | (u64)pay;
}

static __device__ __forceinline__ float redux16(float v) {
    v += __shfl_xor(v, 1); v += __shfl_xor(v, 2); v += __shfl_xor(v, 4); v += __shfl_xor(v, 8);
    return v;
}
static __device__ __forceinline__ float sum64(float v) {
    #pragma unroll
    for (int o = 32; o > 0; o >>= 1) v += __shfl_xor(v, o);
    return v;
}
static __device__ __forceinline__ float expc(float x) { return __expf(fminf(x, 60.f)); }
static __device__ __forceinline__ float fast_tanh(float x) {
    float xc = fminf(fmaxf(x, -15.f), 15.f);
    float e = __expf(2.f * xc);
    return (e - 1.f) / (e + 1.f);
}
// broadcast-buffer swizzle: element d at physical dword d ^ (((d>>5)&7)<<2)
static __device__ __forceinline__ int swz(int d) { return d ^ (((d >> 5) & 7) << 2); }

// expand F(0)..F(7) -- keeps every register-array access compile-time constant
#define RPT8(F) F(0) F(1) F(2) F(3) F(4) F(5) F(6) F(7)

// ---------------- projection GEMM (unchanged) ----------------
__global__ __launch_bounds__(256) void proj_kernel(const float* __restrict__ x,
                                                   const float* __restrict__ Wxz,
                                                   float* __restrict__ xp,
                                                   float* __restrict__ z) {
    __shared__ float As[16][66];
    __shared__ float Bs[16][66];
    const int m0 = blockIdx.x * 64;
    const int n0 = blockIdx.y * 64;
    const int tid = threadIdx.x;
    const int tm = tid / 16, tn = tid % 16;
    float c[4][4] = {};
    for (int k0 = 0; k0 < 512; k0 += 16) {
        const int r = tid >> 2, c4 = (tid & 3) * 4;
        float4 a4 = *(const float4*)(x + (size_t)(m0 + r) * 512 + k0 + c4);
        float4 b4 = *(const float4*)(Wxz + (size_t)(n0 + r) * 512 + k0 + c4);
        As[c4 + 0][r] = a4.x; As[c4 + 1][r] = a4.y; As[c4 + 2][r] = a4.z; As[c4 + 3][r] = a4.w;
        Bs[c4 + 0][r] = b4.x; Bs[c4 + 1][r] = b4.y; Bs[c4 + 2][r] = b4.z; Bs[c4 + 3][r] = b4.w;
        __syncthreads();
        #pragma unroll
        for (int k = 0; k < 16; ++k) {
            float a0 = As[k][tm * 4 + 0], a1 = As[k][tm * 4 + 1];
            float a2 = As[k][tm * 4 + 2], a3 = As[k][tm * 4 + 3];
            float b0 = Bs[k][tn * 4 + 0], b1 = Bs[k][tn * 4 + 1];
            float b2 = Bs[k][tn * 4 + 2], b3 = Bs[k][tn * 4 + 3];
            c[0][0] += a0 * b0; c[0][1] += a0 * b1; c[0][2] += a0 * b2; c[0][3] += a0 * b3;
            c[1][0] += a1 * b0; c[1][1] += a1 * b1; c[1][2] += a1 * b2; c[1][3] += a1 * b3;
            c[2][0] += a2 * b0; c[2][1] += a2 * b1; c[2][2] += a2 * b2; c[2][3] += a2 * b3;
            c[3][0] += a3 * b0; c[3][1] += a3 * b1; c[3][2] += a3 * b2; c[3][3] += a3 * b3;
        }
        __syncthreads();
    }
    #pragma unroll
    for (int i = 0; i < 4; ++i) {
        const int m = m0 + tm * 4 + i;
        #pragma unroll
        for (int j = 0; j < 4; ++j) {
            const int e = n0 + tn * 4 + j;
            if (e < 512) xp[(size_t)m * 512 + e] = c[i][j];
            else         z[(size_t)m * 512 + (e - 512)] = c[i][j];
        }
    }
}

// ---------------- recurrence: 64 blocks = 8 batches x 8 d-chunks ----------------
// 1024-thread TAPE-IN-REGISTERS single-hop design (R5 dataflow, verified correct).
// CHANGE vs R5: the three per-thread register arrays are NAMED SCALARS with fully
// macro-expanded bodies (rule #20: runtime-indexed local arrays defeat SROA and
// land in scratch -- R3/R4/R5's VGPR_Count 128/128/64 with catastrophic slowdown
// was scratch streaming, not a true register test). 96 floats resident + ~30
// temps fits the 128-VGPR bracket at 1024 thr (4 waves/SIMD).
__global__ __launch_bounds__(1024, 4) void rec_kernel(
    const float* __restrict__ tape0, const float* __restrict__ hwork0,
    const float* __restrict__ W_h, const float* __restrict__ b_h,
    const float* __restrict__ W_write,
    const float* __restrict__ g_z, const float* __restrict__ g_r,
    const float* __restrict__ g_h, const float* __restrict__ b_gate,
    const float* __restrict__ Zbuf,
    float* __restrict__ out, float* __restrict__ tape_out,
    u64* hA, u64* cA) {
    __shared__ __align__(16) float hw2f[512];      // full h(t), swizzled
    __shared__ __align__(16) float wvpf[2][512];   // wv double-buffer, swizzled
    __shared__ __align__(16) float red[64][68];    // rv scatter pad
    __shared__ float hnc[64], rvc[64];
    __shared__ float a_l[64], c1_l[64];
    __shared__ float ws_l[64], q0_l[64], hhc[64];
    __shared__ float hwv_s;

    const int b = blockIdx.x & 7, s = blockIdx.x >> 3;   // batch -> XCD, chunk
    const int tid = threadIdx.x, lane = tid & 63, wid = tid >> 6;
    const int nrow = tid >> 4, l = tid & 15;
    const int ls4 = (l & 7) << 2;                        // swizzle XOR in dwords
    const int half = tid & 1, jj = tid >> 1;             // W_write ownership
    const int d0 = s * 64;
    const int lbase = l * 32;
    const float scale = 0.044194173824159216f;           // 1/sqrt(512)

    // --- resident state: 96 named VGPRs ---
    float4 t0, t1, t2, t3, t4_, t5, t6, t7;      // tape[nrow][l*32 + 4i ..]
    float4 wh0, wh1, wh2, wh3, wh4, wh5, wh6, wh7;  // W_h[d0+nrow][l*32 + 4i ..]
    float4 ww0, ww1, ww2, ww3, ww4, ww5, ww6, ww7;  // W_write[jj][d0+half*32+4i ..]
    {
        const float4* ts = (const float4*)(tape0 + (size_t)(b * 64 + nrow) * DD + lbase);
        t0 = ts[0]; t1 = ts[1]; t2 = ts[2]; t3 = ts[3];
        t4_ = ts[4]; t5 = ts[5]; t6 = ts[6]; t7 = ts[7];
        const float4* w1 = (const float4*)(W_h + (size_t)(d0 + nrow) * DD + lbase);
        wh0 = w1[0]; wh1 = w1[1]; wh2 = w1[2]; wh3 = w1[3];
        wh4 = w1[4]; wh5 = w1[5]; wh6 = w1[6]; wh7 = w1[7];
        const float4* w2 = (const float4*)(W_write + (size_t)jj * DD + d0 + half * 32);
        ww0 = w2[0]; ww1 = w2[1]; ww2 = w2[2]; ww3 = w2[3];
        ww4 = w2[4]; ww5 = w2[5]; ww6 = w2[6]; ww7 = w2[7];
    }
    float bhr = 0.f, gz = 0.f, gr = 0.f, gh = 0.f, bg = 0.f;
    if (wid == 0) bhr = b_h[d0 + lane];
    if (wid == 1) { gz = g_z[d0 + lane]; gr = g_r[d0 + lane]; gh = g_h[d0 + lane]; bg = b_gate[d0 + lane]; }

    // --- init LDS ---
    if (tid < 512) hw2f[swz(tid)] = hwork0[(size_t)b * DD + tid];
    ((float*)wvpf)[tid] = 0.f;                 // 1024 = 2*512 floats
    if (tid < 64) a_l[tid] = 0.f;
    float xpr = 0.f, zr = 0.f, hr = 0.f;
    if (wid == 0)      xpr = out[((size_t)(b * TT)) * DD + d0 + lane];
    else if (wid == 1) zr  = Zbuf[((size_t)(b * TT)) * DD + d0 + lane];
    __syncthreads();

    // --- bootstrap: q0 = h(-1).tape0, hh = W_h.h(-1) ---
    {
        float q0 = 0.f, hh = 0.f;
        #define BOOT(i) { \
            float4 h4 = *(const float4*)&hw2f[lbase + ((4*i) ^ ls4)]; \
            q0 += t##i.x*h4.x + t##i.y*h4.y + t##i.z*h4.z + t##i.w*h4.w; \
            hh += wh##i.x*h4.x + wh##i.y*h4.y + wh##i.z*h4.z + wh##i.w*h4.w; }
        #define t4 t4_
        RPT8(BOOT)
        #undef t4
        #undef BOOT
        q0 = redux16(q0); hh = redux16(hh);
        if (l == 0) { q0_l[nrow] = q0; hhc[nrow] = hh; }
    }
    __syncthreads();
    if (wid == 0) {
        float er = expc(scale * q0_l[lane]);
        float Zr = sum64(er);
        c1_l[lane] = __fdividef(er, Zr);       // a(-1)=0 -> c1 = r(0), c2 = 0
    }
    __syncthreads();
    if ((l >> 1) == s) {
        const float c1 = c1_l[nrow];
        #define SCAT(i) { float4 v; \
            v.x = c1*t##i.x; v.y = c1*t##i.y; v.z = c1*t##i.z; v.w = c1*t##i.w; \
            *(float4*)&red[nrow][(l & 1) * 32 + 4*i] = v; }
        #define t4 t4_
        RPT8(SCAT)
        #undef t4
    }
    __syncthreads();
    if (wid == 0) {
        float rv = 0.f;
        #pragma unroll 8
        for (int r = 0; r < 64; ++r) rv += red[r][lane];
        float h = fast_tanh(xpr + hhc[lane] + rv + bhr);
        hr = h; hnc[lane] = h; rvc[lane] = rv;
    }
    __syncthreads();

    // ---------------- main scan ----------------
    for (int t = 0; t < TT; ++t) {
        const int p = t & 1;
        const u32 tg = (u32)(t + 1);
        float c2r = 0.f;

        // ---- P1: publish h(t) + c contributions; out(t); prefetch ----
        if (wid == 0) {
            float hn = __shfl_xor(hr, 1);
            if (!(lane & 1))
                astore64(&hA[((size_t)p * 8 + b) * 256 + s * 32 + (lane >> 1)],
                         mkword(pkh2(hr, hn), tg));
            if (t + 1 < TT) xpr = out[((size_t)(b * TT + t + 1)) * DD + d0 + lane];
        }
        {
            float cj = 0.f;
            #define CJ(i) { float4 h4 = *(const float4*)&hnc[half * 32 + 4*i]; \
                cj += ww##i.x*h4.x + ww##i.y*h4.y + ww##i.z*h4.z + ww##i.w*h4.w; }
            RPT8(CJ)
            #undef CJ
            cj += __shfl_xor(cj, 1);           // full cj for j = jj
            float cn = __shfl_xor(cj, 2);      // cj for j^1
            if (!(tid & 3))
                astore64(&cA[(((size_t)p * 8 + b) * 8 + s) * 256 + (tid >> 2)],
                         mkword(pkh2(cj, cn), tg));
        }
        if (wid == 1) {
            float h = hnc[lane];
            float g = zr * gz + rvc[lane] * gr + h * gh + bg;
            g = fminf(fmaxf(g, -20.f), 20.f);
            float sig = 1.f / (1.f + __expf(-g));
            out[((size_t)(b * TT + t)) * DD + d0 + lane] = h * g * sig;
            if (t + 1 < TT) zr = Zbuf[((size_t)(b * TT + t + 1)) * DD + d0 + lane];
        }

        // ---- P2: lerp (registers only), hop shadow ----
        {
            const float an = a_l[nrow];
            const float* wvO = wvpf[1 - p];
            #define LERP(i) { float4 w4 = *(const float4*)&wvO[lbase + ((4*i) ^ ls4)]; \
                t##i.x += an*(w4.x - t##i.x); t##i.y += an*(w4.y - t##i.y); \
                t##i.z += an*(w4.z - t##i.z); t##i.w += an*(w4.w - t##i.w); }
            #define t4 t4_
            RPT8(LERP)
            #undef t4
            #undef LERP
        }

        // ---- P3: poll/gather: wv(t) (sum of 8 chunk contribs) + h(t) ----
        if (tid < 256) {
            const u64* cb = cA + (((size_t)p * 8 + b) * 8) * 256 + tid;
            u64 v0 = aload64(cb + 0 * 256), v1 = aload64(cb + 1 * 256);
            u64 v2 = aload64(cb + 2 * 256), v3 = aload64(cb + 3 * 256);
            u64 v4 = aload64(cb + 4 * 256), v5 = aload64(cb + 5 * 256);
            u64 v6 = aload64(cb + 6 * 256), v7 = aload64(cb + 7 * 256);
            for (;;) {
                u32 m = 0;
                if ((u32)(v0 >> 32) == tg) m |= 1u;   if ((u32)(v1 >> 32) == tg) m |= 2u;
                if ((u32)(v2 >> 32) == tg) m |= 4u;   if ((u32)(v3 >> 32) == tg) m |= 8u;
                if ((u32)(v4 >> 32) == tg) m |= 16u;  if ((u32)(v5 >> 32) == tg) m |= 32u;
                if ((u32)(v6 >> 32) == tg) m |= 64u;  if ((u32)(v7 >> 32) == tg) m |= 128u;
                if (m == 0xffu) break;
                __builtin_amdgcn_s_sleep(1);
                if (!(m & 1u))   v0 = aload64(cb + 0 * 256);
                if (!(m & 2u))   v1 = aload64(cb + 1 * 256);
                if (!(m & 4u))   v2 = aload64(cb + 2 * 256);
                if (!(m & 8u))   v3 = aload64(cb + 3 * 256);
                if (!(m & 16u))  v4 = aload64(cb + 4 * 256);
                if (!(m & 32u))  v5 = aload64(cb + 5 * 256);
                if (!(m & 64u))  v6 = aload64(cb + 6 * 256);
                if (!(m & 128u)) v7 = aload64(cb + 7 * 256);
            }
            float lo = 0.f, hi = 0.f; float2 f;
            f = uph2((u32)v0); lo += f.x; hi += f.y;
            f = uph2((u32)v1); lo += f.x; hi += f.y;
            f = uph2((u32)v2); lo += f.x; hi += f.y;
            f = uph2((u32)v3); lo += f.x; hi += f.y;
            f = uph2((u32)v4); lo += f.x; hi += f.y;
            f = uph2((u32)v5); lo += f.x; hi += f.y;
            f = uph2((u32)v6); lo += f.x; hi += f.y;
            f = uph2((u32)v7); lo += f.x; hi += f.y;
            const int d = 2 * tid;
            *(float2*)&wvpf[p][d ^ (((d >> 5) & 7) << 2)] = make_float2(lo, hi);
        } else if (tid < 512) {
            const int k = tid - 256;
            const u64* hb = hA + ((size_t)p * 8 + b) * 256 + k;
            u64 v = aload64(hb);
            for (;;) {
                if ((u32)(v >> 32) == tg) break;
                __builtin_amdgcn_s_sleep(1);
                v = aload64(hb);
            }
            float2 hp = uph2((u32)v);
            const int d = 2 * k;
            *(float2*)&hw2f[d ^ (((d >> 5) & 7) << 2)] = hp;
        }
        __syncthreads();                                   // B1

        // ---- P4: fused dots: ws = wv.tape^(t-1), q0 = h.tape^(t-1), hh = W_h.h ----
        {
            float ws = 0.f, q0 = 0.f, hh = 0.f;
            const float* wvP = wvpf[p];
            #define DOTS(i) { const int ph = lbase + ((4*i) ^ ls4); \
                float4 w4 = *(const float4*)&wvP[ph]; \
                float4 h4 = *(const float4*)&hw2f[ph]; \
                ws += w4.x*t##i.x + w4.y*t##i.y + w4.z*t##i.z + w4.w*t##i.w; \
                q0 += h4.x*t##i.x + h4.y*t##i.y + h4.z*t##i.z + h4.w*t##i.w; \
                hh += wh##i.x*h4.x + wh##i.y*h4.y + wh##i.z*h4.z + wh##i.w*h4.w; }
            #define t4 t4_
            RPT8(DOTS)
            #undef t4
            #undef DOTS
            ws = redux16(ws); q0 = redux16(q0); hh = redux16(hh);
            if (l == 0) { ws_l[nrow] = ws; q0_l[nrow] = q0; hhc[nrow] = hh; }
            if (nrow == 0) {                   // hwv = h(t).wv(t) on lanes 0..15
                float hwv = 0.f;
                #pragma unroll
                for (int i = 0; i < 8; ++i) {
                    const int ph = lbase + ((4 * i) ^ ls4);
                    float4 w4 = *(const float4*)&wvP[ph];
                    float4 h4 = *(const float4*)&hw2f[ph];
                    hwv += w4.x * h4.x + w4.y * h4.y + w4.z * h4.z + w4.w * h4.w;
                }
                hwv = redux16(hwv);
                if (tid == 0) hwv_s = hwv;
            }
        }
        __syncthreads();                                   // B2

        // ---- P5: softmaxes (wave0); c2 stays in registers ----
        if (wid == 0) {
            float ew = expc(scale * ws_l[lane]);
            float Zw = sum64(ew);
            float a = __fdividef(ew, Zw);
            float q = (1.f - a) * q0_l[lane] + a * hwv_s;
            float er = expc(scale * q);
            float Zr = sum64(er);
            float r = __fdividef(er, Zr);
            a_l[lane] = a;
            c1_l[lane] = r * (1.f - a);
            c2r = sum64(r * a);
        }
        __syncthreads();                                   // B3

        // ---- P6: rv scatter (chunk-col owners) ----
        if ((l >> 1) == s) {
            const float c1 = c1_l[nrow];
            #define t4 t4_
            RPT8(SCAT)
            #undef t4
        }
        __syncthreads();                                   // B4

        // ---- P7: wave0: rv(t+1) + h(t+1) ----
        if (wid == 0) {
            float rv = c2r * wvpf[p][swz(d0 + lane)];
            #pragma unroll 8
            for (int r = 0; r < 64; ++r) rv += red[r][lane];
            float h = fast_tanh(xpr + hhc[lane] + rv + bhr);
            hr = h; hnc[lane] = h; rvc[lane] = rv;
        }
        __syncthreads();                                   // B5
    }

    // ---- epilogue: final lerp (a(T-1), wv(T-1)=wvpf[1]) + write own chunk ----
    if ((l >> 1) == s) {
        const float an = a_l[nrow];
        float* dst = tape_out + ((size_t)(b * 64 + nrow)) * DD + d0 + (l & 1) * 32;
        #define EPI(i) { float4 w4 = *(const float4*)&wvpf[1][lbase + ((4*i) ^ ls4)]; \
            float4 v = t##i; \
            v.x += an*(w4.x - v.x); v.y += an*(w4.y - v.y); \
            v.z += an*(w4.z - v.z); v.w += an*(w4.w - v.w); \
            *(float4*)(dst + 4*i) = v; }
        #define t4 t4_
        RPT8(EPI)
        #undef t4
        #undef EPI
    }
}

extern "C" void kernel_launch(void* const* d_in, const int* in_sizes, int n_in,
                              void* d_out, int out_size, void* d_ws, size_t ws_size,
                              hipStream_t stream) {
    const float* x       = (const float*)d_in[0];   // [8,1024,512]
    const float* tape0   = (const float*)d_in[1];   // [8,64,512]
    const float* hwork0  = (const float*)d_in[2];   // [8,512]
    const float* W_h     = (const float*)d_in[3];   // [512,512]
    const float* W_xz    = (const float*)d_in[4];   // [1024,512]
    const float* b_h     = (const float*)d_in[5];   // [512]
    const float* W_write = (const float*)d_in[6];   // [512,512]
    const float* g_z     = (const float*)d_in[7];
    const float* g_r     = (const float*)d_in[8];
    const float* g_h     = (const float*)d_in[9];
    const float* b_gate  = (const float*)d_in[10];

    float* out  = (float*)d_out;                        // outs [8,1024,512]
    float* tout = out + (size_t)8 * TT * DD;            // tape_final [8,64,512]

    char* ws = (char*)d_ws;
    u64* hA   = (u64*)ws;                               // [2][8][256]      = 32 KB
    u64* cA   = (u64*)(ws + 32768);                     // [2][8][8][256]   = 256 KB
    float* Zbuf = (float*)(ws + 393216);                // 16 MB

    (void)in_sizes; (void)n_in; (void)out_size; (void)ws_size;

    // tags equality-checked against monotone values; 0xAA poison never matches.
    dim3 pgrid(128, 16);
    proj_kernel<<<pgrid, 256, 0, stream>>>(x, W_xz, out, Zbuf);
    rec_kernel<<<64, 1024, 0, stream>>>(tape0, hwork0, W_h, b_h, W_write,
                                        g_z, g_r, g_h, b_gate, Zbuf,
                                        out, tout, hA, cA);
}

// Round 7
// 8342.262 us; speedup vs baseline: 1.5881x; 1.4410x over previous
//
#include <hip/hip_runtime.h>
#include <math.h>

#define TT 1024
#define DD 512

typedef unsigned int u32;
typedef unsigned long long u64;
typedef _Float16 half2_t __attribute__((ext_vector_type(2)));
typedef unsigned long long u64x2 __attribute__((ext_vector_type(2)));

// ---------------- cross-block exchange primitives ----------------
// SLOW/SAFE path (agent scope, LLC-served; R2-proven, always written):
static __device__ __forceinline__ u64 aload64(const u64* p) {
    return __hip_atomic_load(p, __ATOMIC_RELAXED, __HIP_MEMORY_SCOPE_AGENT);
}
static __device__ __forceinline__ void astore64(u64* p, u64 v) {
    __hip_atomic_store(p, v, __ATOMIC_RELAXED, __HIP_MEMORY_SCOPE_AGENT);
}
// FAST path (XCD-local: all 8 blocks of a batch land on one XCD under the
// blockIdx&7 round-robin heuristic; L1 is write-through, sc0 loads bypass L1
// and are served by the XCD-shared L2 instead of LLC/HBM). Correctness NEVER
// depends on placement: consumers fall back to the agent buffer every 16th
// retry, and producers always dual-publish identical payload bits.
static __device__ __forceinline__ u64 lload64(const u64* p) {
    u64 v;
    asm volatile("global_load_dwordx2 %0, %1, off sc0\n\ts_waitcnt vmcnt(0)"
                 : "=&v"(v) : "v"(p) : "memory");
    return v;
}
static __device__ __forceinline__ void lstore64(u64* p, u64 v) {
    asm volatile("global_store_dwordx2 %0, %1, off sc0" :: "v"(p), "v"(v) : "memory");
}

static __device__ __forceinline__ u32 pkh2(float lo, float hi) {
    return __builtin_bit_cast(u32, __builtin_amdgcn_cvt_pkrtz(lo, hi));
}
static __device__ __forceinline__ float2 uph2(u32 v) {
    half2_t h = __builtin_bit_cast(half2_t, v);
    return make_float2((float)h.x, (float)h.y);
}
static __device__ __forceinline__ u64 mkword(u32 pay, u32 tag) {
    return ((u64)tag << 32) | (u64)pay;
}

static __device__ __forceinline__ float redux8(float v) {
    v += __shfl_xor(v, 1); v += __shfl_xor(v, 2); v += __shfl_xor(v, 4); return v;
}
static __device__ __forceinline__ float sum64(float v) {
    #pragma unroll
    for (int o = 32; o > 0; o >>= 1) v += __shfl_xor(v, o);
    return v;
}
static __device__ __forceinline__ float expc(float x) { return __expf(fminf(x, 60.f)); }
static __device__ __forceinline__ float fast_tanh(float x) {
    float xc = fminf(fmaxf(x, -15.f), 15.f);
    float e = __expf(2.f * xc);
    return (e - 1.f) / (e + 1.f);
}

// ---------------- projection GEMM (unchanged) ----------------
__global__ __launch_bounds__(256) void proj_kernel(const float* __restrict__ x,
                                                   const float* __restrict__ Wxz,
                                                   float* __restrict__ xp,
                                                   float* __restrict__ z) {
    __shared__ float As[16][66];
    __shared__ float Bs[16][66];
    const int m0 = blockIdx.x * 64;
    const int n0 = blockIdx.y * 64;
    const int tid = threadIdx.x;
    const int tm = tid / 16, tn = tid % 16;
    float c[4][4] = {};
    for (int k0 = 0; k0 < 512; k0 += 16) {
        const int r = tid >> 2, c4 = (tid & 3) * 4;
        float4 a4 = *(const float4*)(x + (size_t)(m0 + r) * 512 + k0 + c4);
        float4 b4 = *(const float4*)(Wxz + (size_t)(n0 + r) * 512 + k0 + c4);
        As[c4 + 0][r] = a4.x; As[c4 + 1][r] = a4.y; As[c4 + 2][r] = a4.z; As[c4 + 3][r] = a4.w;
        Bs[c4 + 0][r] = b4.x; Bs[c4 + 1][r] = b4.y; Bs[c4 + 2][r] = b4.z; Bs[c4 + 3][r] = b4.w;
        __syncthreads();
        #pragma unroll
        for (int k = 0; k < 16; ++k) {
            float a0 = As[k][tm * 4 + 0], a1 = As[k][tm * 4 + 1];
            float a2 = As[k][tm * 4 + 2], a3 = As[k][tm * 4 + 3];
            float b0 = Bs[k][tn * 4 + 0], b1 = Bs[k][tn * 4 + 1];
            float b2 = Bs[k][tn * 4 + 2], b3 = Bs[k][tn * 4 + 3];
            c[0][0] += a0 * b0; c[0][1] += a0 * b1; c[0][2] += a0 * b2; c[0][3] += a0 * b3;
            c[1][0] += a1 * b0; c[1][1] += a1 * b1; c[1][2] += a1 * b2; c[1][3] += a1 * b3;
            c[2][0] += a2 * b0; c[2][1] += a2 * b1; c[2][2] += a2 * b2; c[2][3] += a2 * b3;
            c[3][0] += a3 * b0; c[3][1] += a3 * b1; c[3][2] += a3 * b2; c[3][3] += a3 * b3;
        }
        __syncthreads();
    }
    #pragma unroll
    for (int i = 0; i < 4; ++i) {
        const int m = m0 + tm * 4 + i;
        #pragma unroll
        for (int j = 0; j < 4; ++j) {
            const int e = n0 + tn * 4 + j;
            if (e < 512) xp[(size_t)m * 512 + e] = c[i][j];
            else         z[(size_t)m * 512 + (e - 512)] = c[i][j];
        }
    }
}

// ---------------- recurrence: 64 blocks = 8 batches x 8 d-chunks ----------------
// R1 single-hop full-replica structure (verified, 4766us) with DUAL-PATH exchange.
__global__ __launch_bounds__(512) void rec_kernel(
    const float* __restrict__ tape0, const float* __restrict__ hwork0,
    const float* __restrict__ W_h, const float* __restrict__ b_h,
    const float* __restrict__ W_write,
    const float* __restrict__ g_z, const float* __restrict__ g_r,
    const float* __restrict__ g_h, const float* __restrict__ b_gate,
    const float* __restrict__ Zbuf,
    float* __restrict__ out, float* __restrict__ tape_out,
    u64* hA, u64* cA, u64* hF, u64* cF) {
    __shared__ __align__(16) float tp[64][512];      // 128 KB tape replica (swizzled)
    __shared__ __align__(16) float hw2[8][68];       // full h(t), pitch 68
    __shared__ __align__(16) float wvp[2][8][68];    // wv double-buffer, pitch 68
    __shared__ float red[8][64];                     // rv partial per wave
    __shared__ __align__(16) float hnc[64];
    __shared__ float rvc[64], xpc[64], zc[64];
    __shared__ float a_l[64], c1_l[64], hhc[64], ws_l[64], q0_l[64];
    __shared__ float hwv_s;
    __shared__ float c2_s;

    const int b = blockIdx.x & 7, s = blockIdx.x >> 3;   // batch -> XCD, chunk
    const int tid = threadIdx.x, lane = tid & 63, wid = tid >> 6;
    const int nrow = tid >> 3, l = tid & 7;              // (tape row, 64-col slice)
    const int sw = ((l ^ nrow) & 7) << 2;                // per-thread col XOR (dwords)
    const int d0 = s * 64;
    const float scale = 0.044194173824159216f;           // 1/sqrt(512)

    // --- resident weights (128 VGPRs) ---
    float4 wh[16];    // W_h[d0+nrow][l*64 + 4j..]
    float4 wwc[16];   // W_write[tid][d0 + 4j..]
    {
        const float4* w1 = (const float4*)(W_h + (size_t)(d0 + nrow) * DD + l * 64);
        #pragma unroll
        for (int j = 0; j < 16; ++j) wh[j] = w1[j];
        const float4* w2 = (const float4*)(W_write + (size_t)tid * DD + d0);
        #pragma unroll
        for (int j = 0; j < 16; ++j) wwc[j] = w2[j];
    }
    float bhr = 0.f, gz = 0.f, gr = 0.f, gh = 0.f, bg = 0.f;
    if (wid == 0) bhr = b_h[d0 + lane];
    if (wid == 1) { gz = g_z[d0 + lane]; gr = g_r[d0 + lane]; gh = g_h[d0 + lane]; bg = b_gate[d0 + lane]; }

    // --- init LDS: full tape (swizzled), h(-1), zeros ---
    {
        const float* src = tape0 + (size_t)(b * 64 + nrow) * DD;
        #pragma unroll
        for (int i = 0; i < 16; ++i) {
            float4 v = *(const float4*)(src + l * 64 + 4 * i);
            *(float4*)&tp[nrow][(l * 64 + 4 * i) ^ sw] = v;
        }
    }
    hw2[tid >> 6][tid & 63] = hwork0[(size_t)b * DD + tid];
    {
        float* pw = &wvp[0][0][0];
        for (int i = tid; i < 2 * 8 * 68; i += 512) pw[i] = 0.f;
    }
    if (tid < 64) a_l[tid] = 0.f;
    if (tid == 0) c2_s = 0.f;
    float xpr = 0.f, zr = 0.f;
    if (wid == 2)      xpr = out[((size_t)(b * TT)) * DD + d0 + lane];
    else if (wid == 3) zr  = Zbuf[((size_t)(b * TT)) * DD + d0 + lane];
    __syncthreads();

    // --- bootstrap (fully local, no hop): q0(n)=h(-1).tape, hh=W_h.h(-1) ---
    {
        float q0 = 0.f, hh = 0.f;
        #pragma unroll
        for (int i = 0; i < 16; ++i) {
            float4 t4 = *(const float4*)&tp[nrow][(l * 64 + 4 * i) ^ sw];
            float4 h4 = *(const float4*)&hw2[l][4 * i];
            q0 += t4.x * h4.x + t4.y * h4.y + t4.z * h4.z + t4.w * h4.w;
            hh += wh[i].x * h4.x + wh[i].y * h4.y + wh[i].z * h4.z + wh[i].w * h4.w;
        }
        q0 = redux8(q0); hh = redux8(hh);
        if (l == 0) { q0_l[nrow] = q0; hhc[nrow] = hh; }
    }
    __syncthreads();
    if (wid == 0) {
        float er = expc(scale * q0_l[lane]);
        float Zr = sum64(er);
        c1_l[lane] = __fdividef(er, Zr);   // c1 = r(0) (a(-1)=0 -> c2=0)
    }
    __syncthreads();

    // ---------------- main scan ----------------
    for (int t = 0; t < TT; ++t) {
        const int p = t & 1;
        const u32 tg = (u32)(t + 1);
        const size_t p8b = (size_t)p * 8 + b;

        // ---- A: rv partials over pre-lerp tape (c1/c2 trick); stage xp/z ----
        if (wid == 2)      xpc[lane] = xpr;
        else if (wid == 3) zc[lane] = zr;
        {
            float acc = 0.f;
            #pragma unroll
            for (int k = 0; k < 8; ++k)
                acc += c1_l[wid * 8 + k] * tp[wid * 8 + k][(d0 + lane) ^ (((s ^ k) & 7) << 2)];
            red[wid][lane] = acc;
        }
        __syncthreads();                                   // B1
        // ---- B: h(t) chunk (wave0) ----
        if (wid == 0) {
            float rv = c2_s * wvp[1 - p][s][lane];
            #pragma unroll
            for (int w = 0; w < 8; ++w) rv += red[w][lane];
            rvc[lane] = rv;
            hnc[lane] = fast_tanh(xpc[lane] + hhc[lane] + rv + bhr);
        }
        __syncthreads();                                   // B2
        // ---- C: publish h chunk + full-D c contribution (DUAL PATH); out(t) ----
        if (wid == 0 && !(lane & 1)) {
            u64 w = mkword(pkh2(hnc[lane], hnc[lane + 1]), tg);
            const size_t idx = p8b * 256 + s * 32 + (lane >> 1);
            lstore64(&hF[idx], w);
            astore64(&hA[idx], w);
        }
        {
            float cj = 0.f;
            #pragma unroll
            for (int j = 0; j < 16; ++j) {
                float4 h4 = *(const float4*)&hnc[4 * j];
                cj += wwc[j].x * h4.x + wwc[j].y * h4.y + wwc[j].z * h4.z + wwc[j].w * h4.w;
            }
            float cn = __shfl_xor(cj, 1);
            if (!(tid & 1)) {
                u64 w = mkword(pkh2(cj, cn), tg);
                const size_t idx = (p8b * 256 + (size_t)(tid >> 1)) * 8 + s;
                lstore64(&cF[idx], w);
                astore64(&cA[idx], w);
            }
        }
        if (wid == 1) {
            float h = hnc[lane];
            float g = zc[lane] * gz + rvc[lane] * gr + h * gh + bg;
            g = fminf(fmaxf(g, -20.f), 20.f);
            float sig = 1.f / (1.f + __expf(-g));
            out[((size_t)(b * TT + t)) * DD + d0 + lane] = h * g * sig;
        }
        // ---- D: full-tape lerp (hop shadow); fast-poll pre-issue midway ----
        const float an = a_l[nrow];
        #pragma unroll
        for (int i = 0; i < 8; ++i) {
            const int c = (l * 64 + 4 * i) ^ sw;
            float4 t4 = *(const float4*)&tp[nrow][c];
            float4 w4 = *(const float4*)&wvp[1 - p][l][4 * i];
            t4.x += an * (w4.x - t4.x); t4.y += an * (w4.y - t4.y);
            t4.z += an * (w4.z - t4.z); t4.w += an * (w4.w - t4.w);
            *(float4*)&tp[nrow][c] = t4;
        }
        u64x2 a0{}, a1{}, a2{}, a3{};
        u64 vhw = 0;
        const u64* cf = cF + (p8b * 256 + (size_t)tid) * 8;
        const u64* ca = cA + (p8b * 256 + (size_t)tid) * 8;
        const u64* hf = hF + p8b * 256 + (size_t)(tid & 255);
        const u64* hb = hA + p8b * 256 + (size_t)(tid & 255);
        if (tid < 256) {
            asm volatile(
                "global_load_dwordx4 %0, %4, off sc0\n\t"
                "global_load_dwordx4 %1, %4, off offset:16 sc0\n\t"
                "global_load_dwordx4 %2, %4, off offset:32 sc0\n\t"
                "global_load_dwordx4 %3, %4, off offset:48 sc0"
                : "=&v"(a0), "=&v"(a1), "=&v"(a2), "=&v"(a3)
                : "v"(cf) : "memory");
        } else {
            asm volatile("global_load_dwordx2 %0, %1, off sc0"
                         : "=&v"(vhw) : "v"(hf) : "memory");
        }
        #pragma unroll
        for (int i = 8; i < 16; ++i) {
            const int c = (l * 64 + 4 * i) ^ sw;
            float4 t4 = *(const float4*)&tp[nrow][c];
            float4 w4 = *(const float4*)&wvp[1 - p][l][4 * i];
            t4.x += an * (w4.x - t4.x); t4.y += an * (w4.y - t4.y);
            t4.z += an * (w4.z - t4.z); t4.w += an * (w4.w - t4.w);
            *(float4*)&tp[nrow][c] = t4;
        }
        __syncthreads();                                   // B3
        // ---- E: tag-check / gather (fast path + periodic agent fallback) ----
        if (tid < 256) {
            asm volatile("s_waitcnt vmcnt(0)"
                         : "+v"(a0), "+v"(a1), "+v"(a2), "+v"(a3) :: "memory");
            u64 v0 = a0.x, v1 = a0.y, v2 = a1.x, v3 = a1.y;
            u64 v4 = a2.x, v5 = a2.y, v6 = a3.x, v7 = a3.y;
            for (int it = 1; ; ++it) {
                u32 m = 0;
                if ((u32)(v0 >> 32) == tg) m |= 1u;   if ((u32)(v1 >> 32) == tg) m |= 2u;
                if ((u32)(v2 >> 32) == tg) m |= 4u;   if ((u32)(v3 >> 32) == tg) m |= 8u;
                if ((u32)(v4 >> 32) == tg) m |= 16u;  if ((u32)(v5 >> 32) == tg) m |= 32u;
                if ((u32)(v6 >> 32) == tg) m |= 64u;  if ((u32)(v7 >> 32) == tg) m |= 128u;
                if (m == 0xffu) break;
                __builtin_amdgcn_s_sleep(1);
                if ((it & 15) == 0) {      // safety net: agent-scope reload
                    v0 = aload64(ca + 0); v1 = aload64(ca + 1);
                    v2 = aload64(ca + 2); v3 = aload64(ca + 3);
                    v4 = aload64(ca + 4); v5 = aload64(ca + 5);
                    v6 = aload64(ca + 6); v7 = aload64(ca + 7);
                } else {                   // fast XCD-local reload
                    asm volatile(
                        "global_load_dwordx4 %0, %4, off sc0\n\t"
                        "global_load_dwordx4 %1, %4, off offset:16 sc0\n\t"
                        "global_load_dwordx4 %2, %4, off offset:32 sc0\n\t"
                        "global_load_dwordx4 %3, %4, off offset:48 sc0"
                        : "=&v"(a0), "=&v"(a1), "=&v"(a2), "=&v"(a3)
                        : "v"(cf) : "memory");
                    asm volatile("s_waitcnt vmcnt(0)"
                                 : "+v"(a0), "+v"(a1), "+v"(a2), "+v"(a3) :: "memory");
                    v0 = a0.x; v1 = a0.y; v2 = a1.x; v3 = a1.y;
                    v4 = a2.x; v5 = a2.y; v6 = a3.x; v7 = a3.y;
                }
            }
            float lo = 0.f, hi = 0.f; float2 f;
            f = uph2((u32)v0); lo += f.x; hi += f.y;
            f = uph2((u32)v1); lo += f.x; hi += f.y;
            f = uph2((u32)v2); lo += f.x; hi += f.y;
            f = uph2((u32)v3); lo += f.x; hi += f.y;
            f = uph2((u32)v4); lo += f.x; hi += f.y;
            f = uph2((u32)v5); lo += f.x; hi += f.y;
            f = uph2((u32)v6); lo += f.x; hi += f.y;
            f = uph2((u32)v7); lo += f.x; hi += f.y;
            wvp[p][tid >> 5][2 * (tid & 31)]     = lo;
            wvp[p][tid >> 5][2 * (tid & 31) + 1] = hi;
        } else {
            const int k = tid - 256;
            asm volatile("s_waitcnt vmcnt(0)" : "+v"(vhw) :: "memory");
            for (int it = 1; ; ++it) {
                if ((u32)(vhw >> 32) == tg) break;
                __builtin_amdgcn_s_sleep(1);
                vhw = ((it & 15) == 0) ? aload64(hb) : lload64(hf);
            }
            float2 hp = uph2((u32)vhw);
            hw2[k >> 5][2 * (k & 31)]     = hp.x;
            hw2[k >> 5][2 * (k & 31) + 1] = hp.y;
        }
        __syncthreads();                                   // B4
        // ---- F: local dots ws/q0 vs tape(t-1) + NEXT-step hh (folded) + hwv ----
        {
            float ws = 0.f, q0 = 0.f, hh = 0.f;
            #pragma unroll
            for (int i = 0; i < 16; ++i) {
                float4 t4 = *(const float4*)&tp[nrow][(l * 64 + 4 * i) ^ sw];
                float4 w4 = *(const float4*)&wvp[p][l][4 * i];
                float4 h4 = *(const float4*)&hw2[l][4 * i];
                ws += w4.x * t4.x + w4.y * t4.y + w4.z * t4.z + w4.w * t4.w;
                q0 += h4.x * t4.x + h4.y * t4.y + h4.z * t4.z + h4.w * t4.w;
                hh += wh[i].x * h4.x + wh[i].y * h4.y + wh[i].z * h4.z + wh[i].w * h4.w;
            }
            ws = redux8(ws); q0 = redux8(q0); hh = redux8(hh);
            if (l == 0) { ws_l[nrow] = ws; q0_l[nrow] = q0; hhc[nrow] = hh; }
        }
        if (wid == 1) {    // hwv = h(t).wv(t)
            const int r8 = lane >> 3, c8 = (lane & 7) * 8;
            float acc = 0.f;
            #pragma unroll
            for (int k = 0; k < 8; ++k) acc += hw2[r8][c8 + k] * wvp[p][r8][c8 + k];
            acc = sum64(acc);
            if (lane == 0) hwv_s = acc;
        }
        if (wid == 2 && t + 1 < TT)      xpr = out[((size_t)(b * TT + t + 1)) * DD + d0 + lane];
        else if (wid == 3 && t + 1 < TT) zr  = Zbuf[((size_t)(b * TT + t + 1)) * DD + d0 + lane];
        __syncthreads();                                   // B5
        // ---- G: both softmaxes locally (wave0), fused next-read-score ----
        if (wid == 0) {
            float ew = expc(scale * ws_l[lane]);
            float Zw = sum64(ew);
            float a = __fdividef(ew, Zw);
            float q = (1.f - a) * q0_l[lane] + a * hwv_s;
            float er = expc(scale * q);
            float Zr = sum64(er);
            float r = __fdividef(er, Zr);
            a_l[lane] = a;
            c1_l[lane] = r * (1.f - a);
            float c2 = sum64(r * a);
            if (lane == 0) c2_s = c2;
        }
        __syncthreads();                                   // B6
    }

    // ---- epilogue: final lerp (a(T-1), wv(T-1)=wvp[1]) + write own chunk ----
    {
        const float an = a_l[nrow];
        const int esw = ((s ^ nrow) & 7) << 2;
        float* dst = tape_out + ((size_t)(b * 64 + nrow)) * DD;
        #pragma unroll
        for (int i = 0; i < 2; ++i) {
            const int c0 = d0 + l * 8 + 4 * i;
            float4 t4 = *(const float4*)&tp[nrow][c0 ^ esw];
            float4 w4 = *(const float4*)&wvp[1][s][l * 8 + 4 * i];
            t4.x += an * (w4.x - t4.x); t4.y += an * (w4.y - t4.y);
            t4.z += an * (w4.z - t4.z); t4.w += an * (w4.w - t4.w);
            *(float4*)(dst + c0) = t4;
        }
    }
}

extern "C" void kernel_launch(void* const* d_in, const int* in_sizes, int n_in,
                              void* d_out, int out_size, void* d_ws, size_t ws_size,
                              hipStream_t stream) {
    const float* x       = (const float*)d_in[0];   // [8,1024,512]
    const float* tape0   = (const float*)d_in[1];   // [8,64,512]
    const float* hwork0  = (const float*)d_in[2];   // [8,512]
    const float* W_h     = (const float*)d_in[3];   // [512,512]
    const float* W_xz    = (const float*)d_in[4];   // [1024,512]
    const float* b_h     = (const float*)d_in[5];   // [512]
    const float* W_write = (const float*)d_in[6];   // [512,512]
    const float* g_z     = (const float*)d_in[7];
    const float* g_r     = (const float*)d_in[8];
    const float* g_h     = (const float*)d_in[9];
    const float* b_gate  = (const float*)d_in[10];

    float* out  = (float*)d_out;                        // outs [8,1024,512]
    float* tout = out + (size_t)8 * TT * DD;            // tape_final [8,64,512]

    char* ws = (char*)d_ws;
    u64* hA   = (u64*)ws;                               // [2][8][256]        32 KB
    u64* cA   = (u64*)(ws + 32768);                     // [2][8][256][8]    256 KB
    u64* hF   = (u64*)(ws + 294912);                    // [2][8][256]        32 KB
    u64* cF   = (u64*)(ws + 327680);                    // [2][8][256][8]    256 KB
    float* Zbuf = (float*)(ws + 593920);                // 16 MB

    (void)in_sizes; (void)n_in; (void)out_size; (void)ws_size;

    // tags equality-checked against monotone values; poison never matches.
    dim3 pgrid(128, 16);
    proj_kernel<<<pgrid, 256, 0, stream>>>(x, W_xz, out, Zbuf);
    rec_kernel<<<64, 512, 0, stream>>>(tape0, hwork0, W_h, b_h, W_write,
                                       g_z, g_r, g_h, b_gate, Zbuf,
                                       out, tout, hA, cA, hF, cF);
}